// Round 14
// baseline (204.194 us; speedup 1.0000x reference)
//
#include <hip/hip_runtime.h>

#define D_MODEL 1024
#define NUM_HEADS 16
#define D_HEAD 64
#define BATCH 2
#define SEQ 2048
#define MTOT (BATCH * SEQ) /* 4096 */
#define PLANE ((size_t)MTOT * D_MODEL)
#define QSCALE 0.1803368801f /* 0.125 * log2(e) : folds 1/sqrt(dh) and exp->exp2 */

typedef unsigned short us;
typedef __bf16 bf16x8 __attribute__((ext_vector_type(8)));
typedef float floatx4 __attribute__((ext_vector_type(4)));
typedef float floatx16 __attribute__((ext_vector_type(16)));

// ---------- bf16 helpers ----------
__device__ __forceinline__ unsigned int f2bf(float f) {
  union { float f; unsigned int i; } v; v.f = f;
  unsigned int r = v.i + 0x7FFFu + ((v.i >> 16) & 1u); // RNE
  return r >> 16;
}
__device__ __forceinline__ unsigned int f2bf_tr(float f) {
  union { float f; unsigned int i; } v; v.f = f;
  return v.i >> 16;
}

// ---------- fused f32 -> bf16 conversion: x, Wq, Wk, Wv, Wo in one launch ----------
__global__ __launch_bounds__(256) void convert_all(const float* __restrict__ x,
                                                   const float* __restrict__ Wq,
                                                   const float* __restrict__ Wk,
                                                   const float* __restrict__ Wv,
                                                   const float* __restrict__ Wo,
                                                   us* __restrict__ xbf,
                                                   us* __restrict__ Wqkv,
                                                   us* __restrict__ Wobf) {
  const int i = blockIdx.x * 256 + threadIdx.x;  // float4 index
  const float* src;
  us* dst;
  if (i < (1 << 20)) {  // x: 4M elems = 1M float4
    src = x + (size_t)i * 4;
    dst = xbf + (size_t)i * 4;
  } else {
    const int j = i - (1 << 20);
    const int w = j >> 18;                // 0..3 (each W = 256K float4)
    const int o = j & ((1 << 18) - 1);
    if (w < 3) {
      const float* ws = (w == 0) ? Wq : (w == 1) ? Wk : Wv;
      src = ws + (size_t)o * 4;
      dst = Wqkv + (size_t)w * (D_MODEL * D_MODEL) + (size_t)o * 4;
    } else {
      src = Wo + (size_t)o * 4;
      dst = Wobf + (size_t)o * 4;
    }
  }
  float4 v = *(const float4*)src;
  uint2 pk;
  pk.x = f2bf(v.x) | (f2bf(v.y) << 16);
  pk.y = f2bf(v.z) | (f2bf(v.w) << 16);
  *(uint2*)dst = pk;
}

// ---------- MFMA GEMM: C(M,N) = A(M,K) * B(N,K)^T, bf16 inputs, fp32 acc ----------
// 2-PHASE PIPELINE (r5/r10 verified, session-best GEMM structure): double-
// buffered global_load_lds staging; t+1 stage ISSUED before compute(t); ONE
// barrier per K-step. CMODE 1 (fused QKV, N=3072): plane0 -> Q*QSCALE,
// plane1 -> K, plane2 -> V written TRANSPOSED as Vt[b][h][d][s].
template <int CMODE>
__global__ __launch_bounds__(256) void gemm_mfma(const us* __restrict__ A,
                                                 const us* __restrict__ B,
                                                 void* __restrict__ Cv,
                                                 int M, int N, int K) {
  __shared__ __bf16 As[2][128 * 32];
  __shared__ __bf16 Bs[2][128 * 32];
  const int tid = threadIdx.x;
  const int wid = tid >> 6;
  const int lane = tid & 63;
  const int bm = blockIdx.y * 128;
  const int bn = blockIdx.x * 128;
  const int wm = (wid & 1) * 64;
  const int wn = (wid >> 1) * 64;
  const int lr = lane & 15;
  const int quad = lane >> 4;

  floatx4 acc[4][4] = {};
  const int cb0 = wid * 128;

  auto stage = [&](int buf, int k0) {
#pragma unroll
    for (int p = 0; p < 2; ++p) {
      const int cb = cb0 + p * 64;
      const int c = cb + lane;
      const us* ga = A + (size_t)(bm + (c >> 2)) * K + (k0 + (c & 3) * 8);
      const us* gb = B + (size_t)(bn + (c >> 2)) * K + (k0 + (c & 3) * 8);
      __builtin_amdgcn_global_load_lds((const __attribute__((address_space(1))) void*)ga,
                                       (__attribute__((address_space(3))) void*)(&As[buf][cb * 8]),
                                       16, 0, 0);
      __builtin_amdgcn_global_load_lds((const __attribute__((address_space(1))) void*)gb,
                                       (__attribute__((address_space(3))) void*)(&Bs[buf][cb * 8]),
                                       16, 0, 0);
    }
  };

  stage(0, 0);
  __syncthreads();  // compiler inserts vmcnt(0): prologue tile landed

  int cur = 0;
  for (int k0 = 0; k0 < K; k0 += 32) {
    if (k0 + 32 < K) stage(cur ^ 1, k0 + 32);  // issue next-tile DMA first

    bf16x8 a[4], b[4];
#pragma unroll
    for (int i = 0; i < 4; ++i)
      a[i] = *(const bf16x8*)&As[cur][(wm + i * 16 + lr) * 32 + quad * 8];
#pragma unroll
    for (int j = 0; j < 4; ++j)
      b[j] = *(const bf16x8*)&Bs[cur][(wn + j * 16 + lr) * 32 + quad * 8];
#pragma unroll
    for (int i = 0; i < 4; ++i)
#pragma unroll
      for (int j = 0; j < 4; ++j)
        acc[i][j] = __builtin_amdgcn_mfma_f32_16x16x32_bf16(a[i], b[j], acc[i][j], 0, 0, 0);

    __syncthreads();  // vmcnt(0)+lgkmcnt(0): next buf ready, cur reads done
    cur ^= 1;
  }

  // C/D layout: col = lane&15, row = quad*4 + reg (verified r3/r4/r6)
#pragma unroll
  for (int i = 0; i < 4; ++i) {
#pragma unroll
    for (int j = 0; j < 4; ++j) {
      const int col = bn + wn + j * 16 + lr;
      if constexpr (CMODE == 1) {
        us* dst = (us*)Cv;
        const int plane = col >> 10;
        if (plane < 2) {
          const float s = (plane == 0) ? QSCALE : 1.0f;
#pragma unroll
          for (int r = 0; r < 4; ++r) {
            const int row = bm + wm + i * 16 + quad * 4 + r;
            dst[(size_t)plane * PLANE + (size_t)row * 1024 + (col & 1023)] =
                (us)f2bf(acc[i][j][r] * s);
          }
        } else {
          // V transposed: Vt[((b*16+h)*64+d)*2048 + s]; r-consecutive => s-consecutive
          const int d = col & 63;
          const int hh = (col >> 6) & 15;
          const int row0 = bm + wm + i * 16 + quad * 4;
          const int bb = row0 >> 11;
          const int ss = row0 & 2047;
          uint2 pk;
          pk.x = f2bf(acc[i][j][0]) | (f2bf(acc[i][j][1]) << 16);
          pk.y = f2bf(acc[i][j][2]) | (f2bf(acc[i][j][3]) << 16);
          *(uint2*)&dst[2 * PLANE + ((size_t)((bb * 16 + hh) * 64 + d)) * 2048 + ss] = pk;
        }
      } else {
#pragma unroll
        for (int r = 0; r < 4; ++r) {
          const int row = bm + wm + i * 16 + quad * 4 + r;
          ((float*)Cv)[(size_t)row * N + col] = acc[i][j][r];
        }
      }
    }
  }
}

// ---------- MFMA GEMM, BM=128 x BN=64 tile (output projection, r10-verified) ----------
__global__ __launch_bounds__(256) void gemm_n64(const us* __restrict__ A,
                                                const us* __restrict__ B,
                                                float* __restrict__ C,
                                                int M, int N, int K) {
  __shared__ __bf16 As[2][128 * 32];
  __shared__ __bf16 Bs[2][64 * 32];
  const int tid = threadIdx.x;
  const int wid = tid >> 6;
  const int lane = tid & 63;
  const int bm = blockIdx.y * 128;
  const int bn = blockIdx.x * 64;
  const int wm = wid * 32;
  const int lr = lane & 15;
  const int quad = lane >> 4;

  floatx4 acc[2][4] = {};

  auto stage = [&](int buf, int k0) {
#pragma unroll
    for (int p = 0; p < 2; ++p) {
      const int cb = wid * 128 + p * 64;
      const int c = cb + lane;
      const us* ga = A + (size_t)(bm + (c >> 2)) * K + (k0 + (c & 3) * 8);
      __builtin_amdgcn_global_load_lds((const __attribute__((address_space(1))) void*)ga,
                                       (__attribute__((address_space(3))) void*)(&As[buf][cb * 8]),
                                       16, 0, 0);
    }
    const int cb2 = wid * 64;
    const int c2 = cb2 + lane;
    const us* gb = B + (size_t)(bn + (c2 >> 2)) * K + (k0 + (c2 & 3) * 8);
    __builtin_amdgcn_global_load_lds((const __attribute__((address_space(1))) void*)gb,
                                     (__attribute__((address_space(3))) void*)(&Bs[buf][cb2 * 8]),
                                     16, 0, 0);
  };

  stage(0, 0);
  __syncthreads();

  int cur = 0;
  for (int k0 = 0; k0 < K; k0 += 32) {
    if (k0 + 32 < K) stage(cur ^ 1, k0 + 32);

    bf16x8 a[2], b[4];
#pragma unroll
    for (int i = 0; i < 2; ++i)
      a[i] = *(const bf16x8*)&As[cur][(wm + i * 16 + lr) * 32 + quad * 8];
#pragma unroll
    for (int j = 0; j < 4; ++j)
      b[j] = *(const bf16x8*)&Bs[cur][(j * 16 + lr) * 32 + quad * 8];
#pragma unroll
    for (int i = 0; i < 2; ++i)
#pragma unroll
      for (int j = 0; j < 4; ++j)
        acc[i][j] = __builtin_amdgcn_mfma_f32_16x16x32_bf16(a[i], b[j], acc[i][j], 0, 0, 0);

    __syncthreads();
    cur ^= 1;
  }

#pragma unroll
  for (int i = 0; i < 2; ++i) {
#pragma unroll
    for (int j = 0; j < 4; ++j) {
      const int col = bn + j * 16 + lr;
#pragma unroll
      for (int r = 0; r < 4; ++r) {
        const int row = bm + wm + i * 16 + quad * 4 + r;
        C[(size_t)row * N + col] = acc[i][j][r];
      }
    }
  }
}

// ---------- MFMA causal flash attention: 32x32x16 MFMA, 32 q-rows/wave ----------
// LDS-pipe-bound (r3 accounting, every round since). The 32x32x16 shape gives
// 2x FLOP per b128 fragment read (32k vs 16k per 4-VGPR operand) and ~25% more
// FLOP/cyc on the MFMA pipe. Per 64-key x 32-qrow wave-tile: 20 b128 + 8 b64
// LDS ops (~288 cyc) vs 528 cyc for the same work at 16x16 -> 1.83x less
// LDS-pipe demand. 4 waves x 32 q-rows = 128-row strips; pairing, staging
// geometry, LDS budget (54KB -> 2 blocks/CU) all r5-verified and unchanged.
// Layouts: C/D col=lane&31, row=(reg&3)+8*(reg>>2)+4*(lane>>5) [guide-verified
// m74/m101]; A/B row/col=lane&31, k=(lane>>5)*8+j (32-row analog of our
// harness-verified 16x16 mapping). l-vector off MFMA: VALU-sum per lane
// (32 keys), halves combined by one __shfl(lane^32) at epilogue.
// S^T = mfma(K,Q): key=row, qrow=col. O^T = mfma(Vt,P): dim=row, qrow=col.
// Blocks bx / bx+256 get complementary strips (s0, 15-s0).
#define ASTR 72 /* us per LDS row */

__global__ __launch_bounds__(256, 2) void attn_mfma(const us* __restrict__ Qb,
                                                    const us* __restrict__ Kb,
                                                    const us* __restrict__ Vtg,
                                                    us* __restrict__ Ob) {
  const int bx = blockIdx.x;
  const int b = bx >> 8;
  const int idx = bx & 255;
  const int h = idx >> 4;
  const int s0 = idx & 15;
  const int strip = b ? (15 - s0) : s0;  // pair (n, n+256): strips sum to 15
  const int q0 = strip * 128;
  const int ntiles = 2 * strip + 2;
  const int tid = threadIdx.x;
  const int w = tid >> 6;        // 0..3
  const int lane = tid & 63;
  const int l31 = lane & 31;
  const int hi = lane >> 5;      // 0/1: k-halves of the 32x32x16 operands

  __shared__ us Ks[2][64 * ASTR];    // K tile [key][dim], double-buffered
  __shared__ us Vs[2][64 * ASTR];    // V tile [dim][key] (pre-transposed)
  __shared__ us Ps[4 * 32 * ASTR];   // per-wave P [qrow 32][key 64]

  const us* kbase = Kb + (size_t)(b * SEQ) * D_MODEL + h * D_HEAD;
  const us* vbase = Vtg + (size_t)((b * 16 + h) * 64) * 2048;
  us* const pg = &Ps[w * 32 * ASTR];

  const int grow = q0 + w * 32;      // wave's first qrow
  const int qrow = grow + l31;       // this lane's qrow (= MFMA col)

  // Q frags (B-operand: col=qrow=l31, k = ks*16 + hi*8 + j)
  const us* qp = Qb + (size_t)(b * SEQ + qrow) * D_MODEL + h * D_HEAD;
  bf16x8 qa[4];
#pragma unroll
  for (int ks = 0; ks < 4; ++ks)
    qa[ks] = *(const bf16x8*)(qp + ks * 16 + hi * 8);

  floatx16 oacc[2] = {};  // [dimblk]: O^T rows dim, col qrow
  float lacc = 0.f;       // per-lane partial row-sum (this lane's 32-key half)

  // staging geometry: 256 threads x 2 units cover one 64x64 bf16 tile
  uint4 kreg[2], vreg[2];
#pragma unroll
  for (int p = 0; p < 2; ++p) {
    const int c = tid + 256 * p;  // row = c>>3, chunk = c&7
    kreg[p] = *(const uint4*)(kbase + (size_t)(c >> 3) * D_MODEL + (c & 7) * 8);
    vreg[p] = *(const uint4*)(vbase + (size_t)(c >> 3) * 2048 + (c & 7) * 8);
  }
#pragma unroll
  for (int p = 0; p < 2; ++p) {
    const int c = tid + 256 * p;
    *(uint4*)&Ks[0][(c >> 3) * ASTR + (c & 7) * 8] = kreg[p];
    *(uint4*)&Vs[0][(c >> 3) * ASTR + (c & 7) * 8] = vreg[p];
  }
  __syncthreads();

  for (int t = 0; t < ntiles; ++t) {
    const int k0 = t * 64;
    const int cur = t & 1;
    const bool more = (t + 1 < ntiles);

    // issue t+1 global loads first: latency hidden behind compute(t)
    if (more) {
      const int kn = k0 + 64;
#pragma unroll
      for (int p = 0; p < 2; ++p) {
        const int c = tid + 256 * p;
        kreg[p] = *(const uint4*)(kbase + (size_t)(kn + (c >> 3)) * D_MODEL + (c & 7) * 8);
        vreg[p] = *(const uint4*)(vbase + (size_t)(c >> 3) * 2048 + kn + (c & 7) * 8);
      }
    }

    // ---- S^T = K Q^T per 32-key block; exp2+mask; b64 P-writes; l VALU-sum ----
#pragma unroll
    for (int kb = 0; kb < 2; ++kb) {
      floatx16 s = {};
#pragma unroll
      for (int ks = 0; ks < 4; ++ks) {
        const bf16x8 kf = *(const bf16x8*)&Ks[cur][(kb * 32 + l31) * ASTR + ks * 16 + hi * 8];
        s = __builtin_amdgcn_mfma_f32_32x32x16_bf16(kf, qa[ks], s, 0, 0, 0);
      }
      const bool needMask = (k0 + kb * 32 + 31 > grow);
      const int keyg = k0 + kb * 32 + 4 * hi;  // + 8*g + r
#pragma unroll
      for (int g = 0; g < 4; ++g) {
        float p[4];
#pragma unroll
        for (int r = 0; r < 4; ++r) {
          float e = __builtin_amdgcn_exp2f(s[4 * g + r]);
          if (needMask && (keyg + 8 * g + r > qrow)) e = 0.f;
          p[r] = e;
        }
        lacc += (p[0] + p[1]) + (p[2] + p[3]);
        uint2 pk;
        pk.x = f2bf_tr(p[0]) | (f2bf_tr(p[1]) << 16);
        pk.y = f2bf_tr(p[2]) | (f2bf_tr(p[3]) << 16);
        *(uint2*)&pg[l31 * ASTR + kb * 32 + 8 * g + 4 * hi] = pk;
      }
    }

    // ---- PV: P B-frags (4, reused over dimblks); V A-frags (8) ----
    bf16x8 pf[4];
#pragma unroll
    for (int ks = 0; ks < 4; ++ks)
      pf[ks] = *(const bf16x8*)&pg[l31 * ASTR + ks * 16 + hi * 8];
#pragma unroll
    for (int db = 0; db < 2; ++db)
#pragma unroll
      for (int ks = 0; ks < 4; ++ks) {
        const bf16x8 vf = *(const bf16x8*)&Vs[cur][(db * 32 + l31) * ASTR + ks * 16 + hi * 8];
        oacc[db] = __builtin_amdgcn_mfma_f32_32x32x16_bf16(vf, pf[ks], oacc[db], 0, 0, 0);
      }

    // ---- write t+1 into the other buffer; single barrier ----
    if (more) {
      const int nxt = cur ^ 1;
#pragma unroll
      for (int p = 0; p < 2; ++p) {
        const int c = tid + 256 * p;
        *(uint4*)&Ks[nxt][(c >> 3) * ASTR + (c & 7) * 8] = kreg[p];
        *(uint4*)&Vs[nxt][(c >> 3) * ASTR + (c & 7) * 8] = vreg[p];
      }
    }
    __syncthreads();
  }

  // ---- epilogue: combine l halves; O^T*inv -> pg [qrow][dim]; 16B stores ----
  const float ltot = lacc + __shfl(lacc, lane ^ 32, 64);
  const float inv = 1.f / ltot;
#pragma unroll
  for (int db = 0; db < 2; ++db)
#pragma unroll
    for (int g = 0; g < 4; ++g) {
      uint2 pk;
      pk.x = f2bf_tr(oacc[db][4 * g + 0] * inv) | (f2bf_tr(oacc[db][4 * g + 1] * inv) << 16);
      pk.y = f2bf_tr(oacc[db][4 * g + 2] * inv) | (f2bf_tr(oacc[db][4 * g + 3] * inv) << 16);
      *(uint2*)&pg[l31 * ASTR + db * 32 + 8 * g + 4 * hi] = pk;
    }
#pragma unroll
  for (int p = 0; p < 4; ++p) {
    const int c = lane + 64 * p;  // row = c>>3 (0..31), chunk = c&7
    *(uint4*)(Ob + (size_t)(b * SEQ + grow + (c >> 3)) * D_MODEL + h * D_HEAD + (c & 7) * 8) =
        *(const uint4*)&pg[(c >> 3) * ASTR + (c & 7) * 8];
  }
}

extern "C" void kernel_launch(void* const* d_in, const int* in_sizes, int n_in,
                              void* d_out, int out_size, void* d_ws, size_t ws_size,
                              hipStream_t stream) {
  const float* x  = (const float*)d_in[0];
  const float* Wq = (const float*)d_in[1];
  const float* Wk = (const float*)d_in[2];
  const float* Wv = (const float*)d_in[3];
  const float* Wo = (const float*)d_in[4];

  // ws: [x_bf | Qb | Kb | Vt | Wobf]; Ab aliases x_bf (x dead after QKV GEMM).
  us* xbf = (us*)d_ws;
  us* Qb  = xbf + PLANE;
  us* Kb  = xbf + 2 * PLANE;
  us* Vt  = xbf + 3 * PLANE;   // Vt[b][h][d][s], 8 MB
  us* Wobf = xbf + 4 * PLANE;  // 2 MB, lives at d_ws+32MB
  us* Ab  = xbf;
  // d_out (16 MB f32) doubles as scratch for fused Wqkv_bf (6 MB) until final GEMM.
  us* Wqkv = (us*)d_out;
  float* out = (float*)d_out;

  convert_all<<<8192, 256, 0, stream>>>(x, Wq, Wk, Wv, Wo, xbf, Wqkv, Wobf);

  gemm_mfma<1><<<dim3(3072 / 128, MTOT / 128), 256, 0, stream>>>(xbf, Wqkv, Qb, MTOT, 3072, D_MODEL);

  attn_mfma<<<512, 256, 0, stream>>>(Qb, Kb, Vt, Ab);

  gemm_n64<<<dim3(D_MODEL / 64, MTOT / 128), 256, 0, stream>>>(Ab, Wobf, out, MTOT, D_MODEL, D_MODEL);
}